// Round 1
// 226.687 us; speedup vs baseline: 1.0215x; 1.0215x over previous
//
#include <hip/hip_runtime.h>
#include <math.h>

#define DIM   1024
#define NROWS 32768
#define RPB   16     // rows per block, loop-free: 2048 blocks x 16 rows = 32768

// native clang vector type: valid target for __builtin_nontemporal_{load,store}
typedef float v4f __attribute__((ext_vector_type(4)));

// per-element correction: c0 + s1*cs1 + c1*cc1 + s2*cs2 + c2*cc2 + s3*cs3 + c3*cc3
__device__ __forceinline__ float fk_elem(float xin,
    float C0, float S1, float C1, float S2, float C2, float S3, float C3)
{
    float s1, c1;
    __sincosf(xin, &s1, &c1);               // native v_sin/v_cos path
    const float s2 = 2.0f * s1 * c1;        // sin(2x)
    const float c2 = 1.0f - 2.0f * s1 * s1; // cos(2x)
    const float s3 = s2 * c1 + c2 * s1;     // sin(3x)
    const float c3 = c2 * c1 - s2 * s1;     // cos(3x)
    float corr = C0;
    corr = fmaf(s1, S1, corr);
    corr = fmaf(c1, C1, corr);
    corr = fmaf(s2, S2, corr);
    corr = fmaf(c2, C2, corr);
    corr = fmaf(s3, S3, corr);
    corr = fmaf(c3, C3, corr);
    return xin + corr;
}

// Thread tid owns dims [4*tid, 4*tid+4). Its 28 coeffs = 7 contiguous float4s
// at coeffs + 28*tid (112B, 16B-aligned) -> NAMED v4f regs (cached, NOT nt).
// 16 rows loaded up-front as named v4fs via nontemporal loads: x/out are a
// pure stream (touched once), nt keeps them from thrashing L2/L3 fill BW.
// RPB=16 doubles outstanding 16B loads/thread vs RPB=8 at the SAME occupancy
// tier: ~110 VGPR stays in the 65..128 band = 4 waves/SIMD either way.
__global__ __launch_bounds__(256, 4) void fourier_kan_kernel(
    const float* __restrict__ x, const float* __restrict__ coeffs,
    float* __restrict__ out)
{
    const int tid = threadIdx.x;
    const int t0  = blockIdx.x * RPB;

    const v4f* cp = reinterpret_cast<const v4f*>(coeffs + (size_t)tid * 28);
    const v4f q0 = cp[0], q1 = cp[1], q2 = cp[2], q3 = cp[3],
              q4 = cp[4], q5 = cp[5], q6 = cp[6];

    const v4f* xr  = reinterpret_cast<const v4f*>(x + (size_t)t0 * DIM) + tid;
    v4f*       orw = reinterpret_cast<v4f*>(out + (size_t)t0 * DIM) + tid;

    // 16 independent nontemporal loads, issued back-to-back
    // (rows are 256 v4fs apart; wave covers 1024B contiguous per row)
#define LOADX(i) const v4f x##i = __builtin_nontemporal_load(xr + (i) * 256);
    LOADX(0)  LOADX(1)  LOADX(2)  LOADX(3)
    LOADX(4)  LOADX(5)  LOADX(6)  LOADX(7)
    LOADX(8)  LOADX(9)  LOADX(10) LOADX(11)
    LOADX(12) LOADX(13) LOADX(14) LOADX(15)
#undef LOADX

    // flat coeff index 7*j+i for dim j, term i:
    // j=0: q0.x q0.y q0.z q0.w q1.x q1.y q1.z
    // j=1: q1.w q2.x q2.y q2.z q2.w q3.x q3.y
    // j=2: q3.z q3.w q4.x q4.y q4.z q4.w q5.x
    // j=3: q5.y q5.z q5.w q6.x q6.y q6.z q6.w
#define FK_ROW(xv, r)                                                         \
    do {                                                                      \
        v4f ov;                                                               \
        ov.x = fk_elem(xv.x, q0.x, q0.y, q0.z, q0.w, q1.x, q1.y, q1.z);       \
        ov.y = fk_elem(xv.y, q1.w, q2.x, q2.y, q2.z, q2.w, q3.x, q3.y);       \
        ov.z = fk_elem(xv.z, q3.z, q3.w, q4.x, q4.y, q4.z, q4.w, q5.x);       \
        ov.w = fk_elem(xv.w, q5.y, q5.z, q5.w, q6.x, q6.y, q6.z, q6.w);       \
        __builtin_nontemporal_store(ov, orw + (r) * 256);                     \
    } while (0)

    FK_ROW(x0, 0);   FK_ROW(x1, 1);   FK_ROW(x2, 2);   FK_ROW(x3, 3);
    FK_ROW(x4, 4);   FK_ROW(x5, 5);   FK_ROW(x6, 6);   FK_ROW(x7, 7);
    FK_ROW(x8, 8);   FK_ROW(x9, 9);   FK_ROW(x10, 10); FK_ROW(x11, 11);
    FK_ROW(x12, 12); FK_ROW(x13, 13); FK_ROW(x14, 14); FK_ROW(x15, 15);
#undef FK_ROW
}

extern "C" void kernel_launch(void* const* d_in, const int* in_sizes, int n_in,
                              void* d_out, int out_size, void* d_ws, size_t ws_size,
                              hipStream_t stream) {
    const float* x      = (const float*)d_in[0];
    const float* coeffs = (const float*)d_in[1];
    float* out          = (float*)d_out;
    (void)in_sizes; (void)n_in; (void)out_size; (void)d_ws; (void)ws_size;

    const int grid = NROWS / RPB;  // 2048 blocks, loop-free
    fourier_kan_kernel<<<grid, 256, 0, stream>>>(x, coeffs, out);
}

// Round 2
// 225.758 us; speedup vs baseline: 1.0257x; 1.0041x over previous
//
#include <hip/hip_runtime.h>
#include <math.h>

#define DIM   1024
#define NROWS 32768
#define RPB   16     // rows per block: 2048 blocks x 16 rows = 32768
#define PF    4      // prefetch pipeline depth (rows in flight per wave)

// native clang vector type: valid target for __builtin_nontemporal_{load,store}
typedef float v4f __attribute__((ext_vector_type(4)));

// per-element correction: c0 + s1*cs1 + c1*cc1 + s2*cs2 + c2*cc2 + s3*cs3 + c3*cc3
__device__ __forceinline__ float fk_elem(float xin,
    float C0, float S1, float C1, float S2, float C2, float S3, float C3)
{
    float s1, c1;
    __sincosf(xin, &s1, &c1);               // native v_sin/v_cos path
    const float s2 = 2.0f * s1 * c1;        // sin(2x)
    const float c2 = 1.0f - 2.0f * s1 * s1; // cos(2x)
    const float s3 = s2 * c1 + c2 * s1;     // sin(3x)
    const float c3 = c2 * c1 - s2 * s1;     // cos(3x)
    float corr = C0;
    corr = fmaf(s1, S1, corr);
    corr = fmaf(c1, C1, corr);
    corr = fmaf(s2, S2, corr);
    corr = fmaf(c2, C2, corr);
    corr = fmaf(s3, S3, corr);
    corr = fmaf(c3, C3, corr);
    return xin + corr;
}

// Thread tid owns dims [4*tid, 4*tid+4); coeffs = 7 contiguous float4s at
// coeffs + 28*tid (L2-resident after first touch).
//
// OCCUPANCY EXPERIMENT vs round 1: replace the 16-row register file (64 VGPR,
// ~110 total -> 4 waves/SIMD) with a 4-deep rotating prefetch pipeline
// (4 x v4f buffers = 16 VGPR; ~60 total). __launch_bounds__(256, 8) pins
// <=64 VGPR -> 8 waves/SIMD = 32 waves/CU, still ONE residency round
// (2048 blocks = 8 blocks/CU). Twice the waves to cover vmcnt stalls and
// trans-pipe bursts. Buffer reuse (WAR on b0..b3) stops the scheduler from
// hoisting all 16 loads and re-inflating pressure.
__global__ __launch_bounds__(256, 8) void fourier_kan_kernel(
    const float* __restrict__ x, const float* __restrict__ coeffs,
    float* __restrict__ out)
{
    const int tid = threadIdx.x;
    const int t0  = blockIdx.x * RPB;

    const v4f* xr  = reinterpret_cast<const v4f*>(x + (size_t)t0 * DIM) + tid;
    v4f*       orw = reinterpret_cast<v4f*>(out + (size_t)t0 * DIM) + tid;

    // issue the critical-path x prefetches first (rows are 256 v4fs apart)
    v4f b0 = __builtin_nontemporal_load(xr + 0 * 256);
    v4f b1 = __builtin_nontemporal_load(xr + 1 * 256);
    v4f b2 = __builtin_nontemporal_load(xr + 2 * 256);
    v4f b3 = __builtin_nontemporal_load(xr + 3 * 256);

    // then the coeff loads (needed before row 0's compute)
    const v4f* cp = reinterpret_cast<const v4f*>(coeffs + (size_t)tid * 28);
    const v4f q0 = cp[0], q1 = cp[1], q2 = cp[2], q3 = cp[3],
              q4 = cp[4], q5 = cp[5], q6 = cp[6];

    // flat coeff index 7*j+i for dim j, term i:
    // j=0: q0.x q0.y q0.z q0.w q1.x q1.y q1.z
    // j=1: q1.w q2.x q2.y q2.z q2.w q3.x q3.y
    // j=2: q3.z q3.w q4.x q4.y q4.z q4.w q5.x
    // j=3: q5.y q5.z q5.w q6.x q6.y q6.z q6.w
#define FK_STEP(buf, r)                                                       \
    do {                                                                      \
        v4f ov;                                                               \
        ov.x = fk_elem(buf.x, q0.x, q0.y, q0.z, q0.w, q1.x, q1.y, q1.z);      \
        ov.y = fk_elem(buf.y, q1.w, q2.x, q2.y, q2.z, q2.w, q3.x, q3.y);      \
        ov.z = fk_elem(buf.z, q3.z, q3.w, q4.x, q4.y, q4.z, q4.w, q5.x);      \
        ov.w = fk_elem(buf.w, q5.y, q5.z, q5.w, q6.x, q6.y, q6.z, q6.w);      \
        __builtin_nontemporal_store(ov, orw + (r) * 256);                     \
        if ((r) + PF < RPB)                                                   \
            buf = __builtin_nontemporal_load(xr + ((r) + PF) * 256);          \
    } while (0)

    FK_STEP(b0, 0);  FK_STEP(b1, 1);  FK_STEP(b2, 2);  FK_STEP(b3, 3);
    FK_STEP(b0, 4);  FK_STEP(b1, 5);  FK_STEP(b2, 6);  FK_STEP(b3, 7);
    FK_STEP(b0, 8);  FK_STEP(b1, 9);  FK_STEP(b2, 10); FK_STEP(b3, 11);
    FK_STEP(b0, 12); FK_STEP(b1, 13); FK_STEP(b2, 14); FK_STEP(b3, 15);
#undef FK_STEP
}

extern "C" void kernel_launch(void* const* d_in, const int* in_sizes, int n_in,
                              void* d_out, int out_size, void* d_ws, size_t ws_size,
                              hipStream_t stream) {
    const float* x      = (const float*)d_in[0];
    const float* coeffs = (const float*)d_in[1];
    float* out          = (float*)d_out;
    (void)in_sizes; (void)n_in; (void)out_size; (void)d_ws; (void)ws_size;

    const int grid = NROWS / RPB;  // 2048 blocks = 8 blocks/CU, one residency round
    fourier_kan_kernel<<<grid, 256, 0, stream>>>(x, coeffs, out);
}